// Round 7
// baseline (305.678 us; speedup 1.0000x reference)
//
#include <hip/hip_runtime.h>

#define BB 2
#define NN 256
#define DD 512
#define HH 8

typedef float f4raw __attribute__((ext_vector_type(4)));

__device__ __forceinline__ float dot4(float4 a, float4 b) {
    return a.x*b.x + a.y*b.y + a.z*b.z + a.w*b.w;
}

__device__ __forceinline__ float4 f4fma(float s, float4 a, float4 acc) {
    acc.x += s * a.x; acc.y += s * a.y; acc.z += s * a.z; acc.w += s * a.w;
    return acc;
}

__device__ __forceinline__ void gload_lds16(const void* g, void* l) {
    __builtin_amdgcn_global_load_lds(
        (const __attribute__((address_space(1))) unsigned int*)g,
        (__attribute__((address_space(3))) unsigned int*)l, 16, 0, 0);
}

// Stage 8 rows x 512 floats (16KB) global->LDS, per-row XOR swizzle.
// 512-thread variant: wave w stages row y=w, halves j. Dest linear
// (wave-uniform base + lane*16), source per-lane pre-swizzled (m173).
__device__ __forceinline__ void stage_swz8(const char* rowbase, float4* dst, int w, int lane) {
    #pragma unroll
    for (int j = 0; j < 2; ++j) {
        const int f0 = w * 128 + j * 64;
        const int y = w;
        const int c = j * 64 + lane;
        gload_lds16(rowbase + (size_t)y * 2048 + ((size_t)(c ^ y) << 4), &dst[f0]);
    }
}

// ---------------- kProj: 3 linear layers, O = X @ W^T + b -----------------
// grid 768 = 3 proj x 16 rowtiles x 16 coltiles (32x32 tile); block 64 (1 wave)
// K-chunk 16, double-buffered, 4x4 micro-tile with stride-8 row interleave
// (rows ty+8i / cols tx+8j -> b128 LDS reads hit all 32 banks, conflict-free).
__global__ __launch_bounds__(64) void kProj(
    const float* __restrict__ in_,
    const float* __restrict__ w0, const float* __restrict__ b0,
    const float* __restrict__ w1, const float* __restrict__ b1,
    const float* __restrict__ w2, const float* __restrict__ b2,
    float* __restrict__ o0, float* __restrict__ o1, float* __restrict__ o2)
{
    __shared__ float4 xs[2][32 * 5];   // [row][e4 0..3], stride 5 f4
    __shared__ float4 ws[2][32 * 5];

    const int t = threadIdx.x;
    const int blk = blockIdx.x;
    const int proj = blk >> 8;
    const int rem = blk & 255;
    const int row0 = (rem >> 4) * 32;
    const int col0 = (rem & 15) * 32;

    const float* W; const float* Bp; float* O;
    if (proj == 0)      { W = w0; Bp = b0; O = o0; }
    else if (proj == 1) { W = w1; Bp = b1; O = o1; }
    else                { W = w2; Bp = b2; O = o2; }

    const float4* X4 = (const float4*)in_ + (size_t)row0 * 128;
    const float4* W4 = (const float4*)W  + (size_t)col0 * 128;

    const int sr = t >> 2, se = t & 3;           // staging: f=t -> row sr, e se
    const int ty = t >> 3, tx = t & 7;           // compute 8x8 thread grid

    // prefetch chunk 0
    float4 rx0 = X4[(size_t)sr * 128 + se];
    float4 rx1 = X4[(size_t)(sr + 16) * 128 + se];
    float4 rw0 = W4[(size_t)sr * 128 + se];
    float4 rw1 = W4[(size_t)(sr + 16) * 128 + se];
    xs[0][sr * 5 + se] = rx0;  xs[0][(sr + 16) * 5 + se] = rx1;
    ws[0][sr * 5 + se] = rw0;  ws[0][(sr + 16) * 5 + se] = rw1;

    float acc[4][4] = {};

    for (int q = 0; q < 32; ++q) {
        __syncthreads();
        const int cur = q & 1;
        if (q < 31) {
            const int ko = (q + 1) * 4;
            rx0 = X4[(size_t)sr * 128 + ko + se];
            rx1 = X4[(size_t)(sr + 16) * 128 + ko + se];
            rw0 = W4[(size_t)sr * 128 + ko + se];
            rw1 = W4[(size_t)(sr + 16) * 128 + ko + se];
        }
        const float4* xb = xs[cur];
        const float4* wb = ws[cur];
        #pragma unroll
        for (int e4 = 0; e4 < 4; ++e4) {
            float4 xr[4], wc[4];
            #pragma unroll
            for (int i = 0; i < 4; ++i) xr[i] = xb[(ty + 8 * i) * 5 + e4];
            #pragma unroll
            for (int j = 0; j < 4; ++j) wc[j] = wb[(tx + 8 * j) * 5 + e4];
            #pragma unroll
            for (int i = 0; i < 4; ++i)
                #pragma unroll
                for (int j = 0; j < 4; ++j)
                    acc[i][j] += dot4(xr[i], wc[j]);
        }
        if (q < 31) {
            const int nxt = cur ^ 1;
            xs[nxt][sr * 5 + se] = rx0;  xs[nxt][(sr + 16) * 5 + se] = rx1;
            ws[nxt][sr * 5 + se] = rw0;  ws[nxt][(sr + 16) * 5 + se] = rw1;
        }
    }

    float bb[4];
    #pragma unroll
    for (int j = 0; j < 4; ++j) bb[j] = Bp[col0 + tx + 8 * j];
    #pragma unroll
    for (int i = 0; i < 4; ++i) {
        const int orow = row0 + ty + 8 * i;
        #pragma unroll
        for (int j = 0; j < 4; ++j)
            O[(size_t)orow * DD + col0 + tx + 8 * j] = acc[i][j] + bb[j];
    }
}

// ---------------- kQkp: qkp[row,h,e] = sum_d q[row,h*64+d]*wrk[h*64+d,e] ----
// grid 2048 = 64 rowgroups(8 rows) x 8 h x 4 e-slices(128); block 256
__global__ __launch_bounds__(256) void kQkp(
    const float* __restrict__ q, const float* __restrict__ wrk,
    float* __restrict__ qkp)
{
    __shared__ float qs[8 * 64];
    const int t = threadIdx.x;
    const int blk = blockIdx.x;
    const int rowg = blk >> 5;
    const int h = (blk >> 2) & 7;
    const int eq = blk & 3;
    const int row0 = rowg * 8;
    {
        const int r = t >> 5, d2 = (t & 31) * 2;
        const float2 tmp = *(const float2*)(q + (size_t)(row0 + r) * DD + h * 64 + d2);
        qs[r * 64 + d2] = tmp.x; qs[r * 64 + d2 + 1] = tmp.y;
    }
    __syncthreads();
    const int e = eq * 128 + (t & 127);
    const int rp = (t >> 7) * 4;
    const float* wcol = wrk + (size_t)(h * 64) * DD + e;
    float a0 = 0, a1 = 0, a2 = 0, a3 = 0;
    #pragma unroll 8
    for (int d = 0; d < 64; ++d) {
        const float wv = wcol[(size_t)d * DD];
        a0 += qs[(rp + 0) * 64 + d] * wv;
        a1 += qs[(rp + 1) * 64 + d] * wv;
        a2 += qs[(rp + 2) * 64 + d] * wv;
        a3 += qs[(rp + 3) * 64 + d] * wv;
    }
    qkp[((size_t)(row0 + rp + 0) * HH + h) * DD + e] = a0;
    qkp[((size_t)(row0 + rp + 1) * HH + h) * DD + e] = a1;
    qkp[((size_t)(row0 + rp + 2) * HH + h) * DD + e] = a2;
    qkp[((size_t)(row0 + rp + 3) * HH + h) * DD + e] = a3;
}

// ---------------- kSk: sk[b,x,h,y] = 0.125*(q.k) + mask ----------------
// grid 2048 = 2b x 8h x 32 xt(8 rows) x 4 yt(64); block 256
__global__ __launch_bounds__(256) void kSk(
    const float* __restrict__ q, const float* __restrict__ k,
    const unsigned char* __restrict__ mask, float* __restrict__ sk)
{
    __shared__ float qs[8 * 65];
    __shared__ float ks[64 * 65];
    const int t = threadIdx.x;
    const int blk = blockIdx.x;
    const int b  = blk >> 10;
    const int h  = (blk >> 7) & 7;
    const int xt = (blk >> 2) & 31;
    const int yt = blk & 3;
    const int x0 = xt * 8, y0 = yt * 64;
    {
        const int r = t >> 5, d2 = (t & 31) * 2;
        const float2 tmp = *(const float2*)(q + (size_t)(b * NN + x0 + r) * DD + h * 64 + d2);
        qs[r * 65 + d2] = tmp.x; qs[r * 65 + d2 + 1] = tmp.y;
    }
    #pragma unroll
    for (int j = 0; j < 8; ++j) {
        const int f = t + 256 * j;
        const int r = f >> 5, d2 = (f & 31) * 2;
        const float2 tmp = *(const float2*)(k + (size_t)(b * NN + y0 + r) * DD + h * 64 + d2);
        ks[r * 65 + d2] = tmp.x; ks[r * 65 + d2 + 1] = tmp.y;
    }
    __syncthreads();
    const int xi = t >> 5, yg = t & 31;
    float a0 = 0, a1 = 0;
    #pragma unroll 8
    for (int d = 0; d < 64; ++d) {
        const float qv = qs[xi * 65 + d];
        a0 += qv * ks[(yg * 2 + 0) * 65 + d];
        a1 += qv * ks[(yg * 2 + 1) * 65 + d];
    }
    a0 *= 0.125f; a1 *= 0.125f;
    const unsigned char* mrow = mask + (size_t)(b * NN + x0 + xi) * NN;
    const int gy = y0 + yg * 2;
    if (mrow[gy + 0]) a0 = -1e9f;
    if (mrow[gy + 1]) a1 = -1e9f;
    float2 st; st.x = a0; st.y = a1;
    *(float2*)(sk + ((size_t)(b * NN + x0 + xi) * HH + h) * NN + gy) = st;
}

// ---------------- kC: full-row flash attention over G + fused epilogue ----
// grid 512 = one block per (b,x); block 512 (8 waves); 32 tiles of 8 y-rows.
// qkp in static LDS (loaded once); wrv GEMV epilogue in-kernel -> om.
// No partials, no merge kernel.
__global__ __launch_bounds__(512) void kC(
    const float* __restrict__ G, const float* __restrict__ sk,
    const float* __restrict__ qkp, const float* __restrict__ v,
    const float* __restrict__ wrv, const float* __restrict__ brv,
    float* __restrict__ om)
{
    __shared__ float4 gbuf[2][1024];   // double-buffered 8x512 G tile, swizzled
    __shared__ float4 qgc[1024];       // qkp [8h][128] swizzled; g_agg in epilogue
    __shared__ float s_l[64];          // scores [8y][8h]
    __shared__ float lL[8];
    __shared__ float xvs[512];

    const int t = threadIdx.x;
    const int lane = t & 63;
    const int w = t >> 6;              // wave 0..7
    const int bid = blockIdx.x;        // b*N + x
    const int b = bid >> 8;

    const char* Grow = (const char*)(G + (size_t)bid * NN * DD);
    stage_swz8((const char*)(qkp + (size_t)bid * HH * DD), qgc, w, lane);
    stage_swz8(Grow, &gbuf[0][0], w, lane);

    // score ids: 16-lane e4-slices; 32 groups = 8y x 4 h-pairs
    const int s_  = t & 15;
    const int sg  = t >> 4;            // 0..31
    const int sy  = sg >> 2;           // y 0..7
    const int h0i = (sg & 3) * 2;      // h pair base
    // accumulate ids: 4 groups x 2 heads x 128 e4-slices
    const int ec4 = t & 127;
    const int hb  = (t >> 7) * 2;
    // x_v ids: 8 heads x 64 dims
    const int hv  = t >> 6;            // == w
    const int dv  = t & 63;
    const int ri  = hv & 1;            // hv in {hb, hb+1}

    float4 gacc0 = {0,0,0,0}, gacc1 = {0,0,0,0};
    float m0 = -3e38f, m1 = -3e38f, l0 = 0, l1 = 0, vx = 0;

    const float* vcol = v + (size_t)(b * NN) * DD + hv * 64 + dv;
    const float* skrow = sk + (size_t)bid * HH * NN;

    __syncthreads();   // qgc + gbuf[0] staged

    int cb = 0;
    for (int tt = 0; tt < 32; ++tt) {
        if (tt < 31)
            stage_swz8(Grow + (size_t)(tt + 1) * 8 * 2048, &gbuf[cb ^ 1][0], w, lane);

        // v loads hoisted (L2; latency hides under score phase)
        float vvs[8];
        #pragma unroll
        for (int y = 0; y < 8; ++y) vvs[y] = vcol[((size_t)tt * 8 + y) * DD];

        // ---- scores: each 16-lane slice computes (y, h-pair) ----
        {
            float a0 = 0, a1 = 0;
            const float4* gb = &gbuf[cb][0];
            #pragma unroll
            for (int i = 0; i < 8; ++i) {
                const int e4 = i * 16 + s_;
                const float4 g0 = gb[sy * 128 + (e4 ^ sy)];
                a0 += dot4(g0, qgc[h0i * 128 + (e4 ^ h0i)]);
                a1 += dot4(g0, qgc[(h0i + 1) * 128 + (e4 ^ (h0i + 1))]);
            }
            #pragma unroll
            for (int mm = 1; mm < 16; mm <<= 1) {
                a0 += __shfl_xor(a0, mm); a1 += __shfl_xor(a1, mm);
            }
            if (s_ < 2) {
                const float val = (s_ == 0) ? a0 : a1;
                const int h = h0i + s_;
                const int gy = tt * 8 + sy;
                s_l[sy * 8 + h] = val * 0.125f + skrow[(size_t)h * NN + gy];
            }
        }
        __syncthreads();

        // ---- scores -> regs (wave-uniform float2 broadcast reads) ----
        float2 sv[8];
        #pragma unroll
        for (int y = 0; y < 8; ++y) sv[y] = *(const float2*)&s_l[y * 8 + hb];

        float mx0 = sv[0].x, mx1 = sv[0].y;
        #pragma unroll
        for (int y = 1; y < 8; ++y) {
            mx0 = fmaxf(mx0, sv[y].x); mx1 = fmaxf(mx1, sv[y].y);
        }
        const float n0 = fmaxf(m0, mx0), rs0 = __expf(m0 - n0);
        const float n1 = fmaxf(m1, mx1), rs1 = __expf(m1 - n1);
        m0 = n0; m1 = n1;
        l0 *= rs0; l1 *= rs1;
        gacc0.x *= rs0; gacc0.y *= rs0; gacc0.z *= rs0; gacc0.w *= rs0;
        gacc1.x *= rs1; gacc1.y *= rs1; gacc1.z *= rs1; gacc1.w *= rs1;
        vx *= ri ? rs1 : rs0;

        // ---- accumulate g_agg (2 heads/thread) + x_v ----
        {
            const float4* gb = &gbuf[cb][0];
            #pragma unroll
            for (int y = 0; y < 8; ++y) {
                const float4 gv = gb[y * 128 + (ec4 ^ y)];
                const float p0 = __expf(sv[y].x - m0); l0 += p0; gacc0 = f4fma(p0, gv, gacc0);
                const float p1 = __expf(sv[y].y - m1); l1 += p1; gacc1 = f4fma(p1, gv, gacc1);
                vx += (ri ? p1 : p0) * vvs[y];
            }
        }
        __syncthreads();
        cb ^= 1;
    }

    // ---- epilogue: g_agg -> LDS (reuse qgc), then wrv GEMV ----
    qgc[(hb + 0) * 128 + ec4] = gacc0;
    qgc[(hb + 1) * 128 + ec4] = gacc1;
    if (ec4 == 0) { lL[hb] = l0; lL[hb + 1] = l1; }
    xvs[hv * 64 + dv] = vx;
    __syncthreads();

    #pragma unroll 2
    for (int oo = 0; oo < 16; ++oo) {
        const int o = sg * 16 + oo;
        const int ho = o >> 6;
        const float4* wr4 = (const float4*)(wrv + (size_t)o * DD);
        float acc = 0;
        #pragma unroll
        for (int i = 0; i < 8; ++i) {
            const int e4 = i * 16 + s_;
            acc += dot4(wr4[e4], qgc[ho * 128 + e4]);
        }
        #pragma unroll
        for (int mm = 1; mm < 16; mm <<= 1) acc += __shfl_xor(acc, mm);
        if (s_ == 0)
            om[(size_t)bid * DD + o] = (xvs[o] + acc) / lL[ho] + brv[o];
    }
}

// ---------------- kE: new_graphs = xl[:,:,None,:] + xr[:,None,:,:] -------
// grid 2048 = 512 bid x 4 y-chunks; block 256; nontemporal streaming stores
__global__ __launch_bounds__(256) void kE(
    const float* __restrict__ xl, const float* __restrict__ xr,
    float* __restrict__ ng)
{
    const int t = threadIdx.x;
    const int blk = blockIdx.x;
    const int bid = blk >> 2;
    const int yc = blk & 3;
    const int b = bid >> 8;
    const int o4 = t & 127;
    const int yh = t >> 7;
    const float4 left = ((const float4*)xl)[(size_t)bid * 128 + o4];
    const float4* xr4 = (const float4*)xr + (size_t)b * NN * 128;
    f4raw* out4 = (f4raw*)ng + (size_t)bid * NN * 128;
    for (int y = yc * 64 + yh; y < yc * 64 + 64; y += 2) {
        const float4 rr = xr4[y * 128 + o4];
        f4raw s;
        s.x = left.x + rr.x; s.y = left.y + rr.y;
        s.z = left.z + rr.z; s.w = left.w + rr.w;
        __builtin_nontemporal_store(s, &out4[y * 128 + o4]);
    }
}

extern "C" void kernel_launch(void* const* d_in, const int* in_sizes, int n_in,
                              void* d_out, int out_size, void* d_ws, size_t ws_size,
                              hipStream_t stream)
{
    (void)in_sizes; (void)n_in; (void)out_size; (void)ws_size;
    const float* x    = (const float*)d_in[0];
    const float* G    = (const float*)d_in[1];
    const unsigned char* mask = (const unsigned char*)d_in[2];
    const float* wq  = (const float*)d_in[3];  const float* bq  = (const float*)d_in[4];
    const float* wk  = (const float*)d_in[5];  const float* bk  = (const float*)d_in[6];
    const float* wv  = (const float*)d_in[7];  const float* bv  = (const float*)d_in[8];
    const float* wo  = (const float*)d_in[9];  const float* bo  = (const float*)d_in[10];
    const float* wl  = (const float*)d_in[11]; const float* bl  = (const float*)d_in[12];
    const float* wr  = (const float*)d_in[13]; const float* br  = (const float*)d_in[14];
    const float* wrk = (const float*)d_in[15]; /* brk unused: softmax-invariant */
    const float* wrv = (const float*)d_in[17]; const float* brv = (const float*)d_in[18];

    float* out  = (float*)d_out;
    float* fout = out;                          // [B,N,D]
    float* ng   = out + (size_t)BB * NN * DD;   // [B,N,N,D]

    // Scratch in the tail of the ng region: all consumed before kE overwrites.
    const size_t ng_f  = (size_t)BB * NN * NN * DD;   // 67,108,864
    const size_t row_f = (size_t)BB * NN * DD;        // 262,144
    const size_t total = row_f * 17;                  // q,k,v,qkp(8),skp(4),om
    float* base = ng + ng_f - total;
    float* q    = base;
    float* k    = q   + row_f;
    float* vv_  = k   + row_f;
    float* qkp  = vv_ + row_f;          // row_f * 8
    float* skp  = qkp + row_f * 8;      // row_f * 4
    float* om   = skp + row_f * 4;      // row_f
    float* xl = (float*)d_ws;           // survives into kE -> d_ws
    float* xr = xl + row_f;

    kProj<<<768, 64, 0, stream>>>(x, wq, bq, wk, bk, wv, bv, q, k, vv_);
    kQkp <<<2048, 256, 0, stream>>>(q, wrk, qkp);
    kSk  <<<2048, 256, 0, stream>>>(q, k, mask, skp);
    kC   <<<512, 512, 0, stream>>>(G, skp, qkp, vv_, wrv, brv, om);
    kProj<<<768, 64, 0, stream>>>(om, wo, bo, wl, bl, wr, br, fout, xl, xr);
    kE   <<<2048, 256, 0, stream>>>(xl, xr, ng);
}

// Round 8
// 291.359 us; speedup vs baseline: 1.0491x; 1.0491x over previous
//
#include <hip/hip_runtime.h>

#define BB 2
#define NN 256
#define DD 512
#define HH 8

typedef float f4raw __attribute__((ext_vector_type(4)));

__device__ __forceinline__ float dot4(float4 a, float4 b) {
    return a.x*b.x + a.y*b.y + a.z*b.z + a.w*b.w;
}

__device__ __forceinline__ float4 f4fma(float s, float4 a, float4 acc) {
    acc.x += s * a.x; acc.y += s * a.y; acc.z += s * a.z; acc.w += s * a.w;
    return acc;
}

__device__ __forceinline__ float4 f4mul(float s, float4 a) {
    a.x *= s; a.y *= s; a.z *= s; a.w *= s; return a;
}

__device__ __forceinline__ void gload_lds16(const void* g, void* l) {
    __builtin_amdgcn_global_load_lds(
        (const __attribute__((address_space(1))) unsigned int*)g,
        (__attribute__((address_space(3))) unsigned int*)l, 16, 0, 0);
}

// Stage 8 rows x 512 floats (16KB) global->LDS with per-row XOR swizzle.
// 4-wave cooperative (used for qkp): dest linear, source pre-swizzled (m173).
__device__ __forceinline__ void stage_swz(const char* rowbase, float4* dst, int w, int lane) {
    #pragma unroll
    for (int j = 0; j < 4; ++j) {
        const int f0 = w * 256 + j * 64;
        const int y = f0 >> 7;
        const int c = (f0 & 127) + lane;
        gload_lds16(rowbase + (size_t)y * 2048 + ((size_t)(c ^ y) << 4), &dst[f0]);
    }
}

// Wave-PRIVATE G staging: wave w stages rows {2w, 2w+1} of the 8-row tile
// (exactly the rows it consumes). 4 gload_lds per wave per tile.
__device__ __forceinline__ void stageG(const char* Grow, int tt, int w, int lane, float4* dst) {
    #pragma unroll
    for (int r = 0; r < 2; ++r) {
        const int yr = 2 * w + r;                       // row-in-tile, swizzle key
        const char* src = Grow + (size_t)(tt * 8 + yr) * 2048;
        #pragma unroll
        for (int j = 0; j < 2; ++j) {
            const int c = j * 64 + lane;
            gload_lds16(src + ((size_t)(c ^ yr) << 4), &dst[r * 128 + j * 64]);
        }
    }
}

// ---------------- kProj: 3 linear layers, O = X @ W^T + b -----------------
// grid 768 = 3 proj x 16 rowtiles x 16 coltiles (32x32 tile); block 64 (1 wave)
__global__ __launch_bounds__(64) void kProj(
    const float* __restrict__ in_,
    const float* __restrict__ w0, const float* __restrict__ b0,
    const float* __restrict__ w1, const float* __restrict__ b1,
    const float* __restrict__ w2, const float* __restrict__ b2,
    float* __restrict__ o0, float* __restrict__ o1, float* __restrict__ o2)
{
    __shared__ float4 xs[2][32 * 5];
    __shared__ float4 ws[2][32 * 5];

    const int t = threadIdx.x;
    const int blk = blockIdx.x;
    const int proj = blk >> 8;
    const int rem = blk & 255;
    const int row0 = (rem >> 4) * 32;
    const int col0 = (rem & 15) * 32;

    const float* W; const float* Bp; float* O;
    if (proj == 0)      { W = w0; Bp = b0; O = o0; }
    else if (proj == 1) { W = w1; Bp = b1; O = o1; }
    else                { W = w2; Bp = b2; O = o2; }

    const float4* X4 = (const float4*)in_ + (size_t)row0 * 128;
    const float4* W4 = (const float4*)W  + (size_t)col0 * 128;

    const int sr = t >> 2, se = t & 3;
    const int ty = t >> 3, tx = t & 7;

    float4 rx0 = X4[(size_t)sr * 128 + se];
    float4 rx1 = X4[(size_t)(sr + 16) * 128 + se];
    float4 rw0 = W4[(size_t)sr * 128 + se];
    float4 rw1 = W4[(size_t)(sr + 16) * 128 + se];
    xs[0][sr * 5 + se] = rx0;  xs[0][(sr + 16) * 5 + se] = rx1;
    ws[0][sr * 5 + se] = rw0;  ws[0][(sr + 16) * 5 + se] = rw1;

    float acc[4][4] = {};

    for (int q = 0; q < 32; ++q) {
        __syncthreads();
        const int cur = q & 1;
        if (q < 31) {
            const int ko = (q + 1) * 4;
            rx0 = X4[(size_t)sr * 128 + ko + se];
            rx1 = X4[(size_t)(sr + 16) * 128 + ko + se];
            rw0 = W4[(size_t)sr * 128 + ko + se];
            rw1 = W4[(size_t)(sr + 16) * 128 + ko + se];
        }
        const float4* xb = xs[cur];
        const float4* wb = ws[cur];
        #pragma unroll
        for (int e4 = 0; e4 < 4; ++e4) {
            float4 xr[4], wc[4];
            #pragma unroll
            for (int i = 0; i < 4; ++i) xr[i] = xb[(ty + 8 * i) * 5 + e4];
            #pragma unroll
            for (int j = 0; j < 4; ++j) wc[j] = wb[(tx + 8 * j) * 5 + e4];
            #pragma unroll
            for (int i = 0; i < 4; ++i)
                #pragma unroll
                for (int j = 0; j < 4; ++j)
                    acc[i][j] += dot4(xr[i], wc[j]);
        }
        if (q < 31) {
            const int nxt = cur ^ 1;
            xs[nxt][sr * 5 + se] = rx0;  xs[nxt][(sr + 16) * 5 + se] = rx1;
            ws[nxt][sr * 5 + se] = rw0;  ws[nxt][(sr + 16) * 5 + se] = rw1;
        }
    }

    float bb[4];
    #pragma unroll
    for (int j = 0; j < 4; ++j) bb[j] = Bp[col0 + tx + 8 * j];
    #pragma unroll
    for (int i = 0; i < 4; ++i) {
        const int orow = row0 + ty + 8 * i;
        #pragma unroll
        for (int j = 0; j < 4; ++j)
            O[(size_t)orow * DD + col0 + tx + 8 * j] = acc[i][j] + bb[j];
    }
}

// ---------------- kQkp ----------------
__global__ __launch_bounds__(256) void kQkp(
    const float* __restrict__ q, const float* __restrict__ wrk,
    float* __restrict__ qkp)
{
    __shared__ float qs[8 * 64];
    const int t = threadIdx.x;
    const int blk = blockIdx.x;
    const int rowg = blk >> 5;
    const int h = (blk >> 2) & 7;
    const int eq = blk & 3;
    const int row0 = rowg * 8;
    {
        const int r = t >> 5, d2 = (t & 31) * 2;
        const float2 tmp = *(const float2*)(q + (size_t)(row0 + r) * DD + h * 64 + d2);
        qs[r * 64 + d2] = tmp.x; qs[r * 64 + d2 + 1] = tmp.y;
    }
    __syncthreads();
    const int e = eq * 128 + (t & 127);
    const int rp = (t >> 7) * 4;
    const float* wcol = wrk + (size_t)(h * 64) * DD + e;
    float a0 = 0, a1 = 0, a2 = 0, a3 = 0;
    #pragma unroll 8
    for (int d = 0; d < 64; ++d) {
        const float wv = wcol[(size_t)d * DD];
        a0 += qs[(rp + 0) * 64 + d] * wv;
        a1 += qs[(rp + 1) * 64 + d] * wv;
        a2 += qs[(rp + 2) * 64 + d] * wv;
        a3 += qs[(rp + 3) * 64 + d] * wv;
    }
    qkp[((size_t)(row0 + rp + 0) * HH + h) * DD + e] = a0;
    qkp[((size_t)(row0 + rp + 1) * HH + h) * DD + e] = a1;
    qkp[((size_t)(row0 + rp + 2) * HH + h) * DD + e] = a2;
    qkp[((size_t)(row0 + rp + 3) * HH + h) * DD + e] = a3;
}

// ---------------- kSk ----------------
__global__ __launch_bounds__(256) void kSk(
    const float* __restrict__ q, const float* __restrict__ k,
    const unsigned char* __restrict__ mask, float* __restrict__ sk)
{
    __shared__ float qs[8 * 65];
    __shared__ float ks[64 * 65];
    const int t = threadIdx.x;
    const int blk = blockIdx.x;
    const int b  = blk >> 10;
    const int h  = (blk >> 7) & 7;
    const int xt = (blk >> 2) & 31;
    const int yt = blk & 3;
    const int x0 = xt * 8, y0 = yt * 64;
    {
        const int r = t >> 5, d2 = (t & 31) * 2;
        const float2 tmp = *(const float2*)(q + (size_t)(b * NN + x0 + r) * DD + h * 64 + d2);
        qs[r * 65 + d2] = tmp.x; qs[r * 65 + d2 + 1] = tmp.y;
    }
    #pragma unroll
    for (int j = 0; j < 8; ++j) {
        const int f = t + 256 * j;
        const int r = f >> 5, d2 = (f & 31) * 2;
        const float2 tmp = *(const float2*)(k + (size_t)(b * NN + y0 + r) * DD + h * 64 + d2);
        ks[r * 65 + d2] = tmp.x; ks[r * 65 + d2 + 1] = tmp.y;
    }
    __syncthreads();
    const int xi = t >> 5, yg = t & 31;
    float a0 = 0, a1 = 0;
    #pragma unroll 8
    for (int d = 0; d < 64; ++d) {
        const float qv = qs[xi * 65 + d];
        a0 += qv * ks[(yg * 2 + 0) * 65 + d];
        a1 += qv * ks[(yg * 2 + 1) * 65 + d];
    }
    a0 *= 0.125f; a1 *= 0.125f;
    const unsigned char* mrow = mask + (size_t)(b * NN + x0 + xi) * NN;
    const int gy = y0 + yg * 2;
    if (mrow[gy + 0]) a0 = -1e9f;
    if (mrow[gy + 1]) a1 = -1e9f;
    float2 st; st.x = a0; st.y = a1;
    *(float2*)(sk + ((size_t)(b * NN + x0 + xi) * HH + h) * NN + gy) = st;
}

// ---------------- kC: barrier-free flash attention over G -----------------
// grid 512 (one block per (b,x)); block 256 = 4 waves. Wave w owns rows
// {2w,2w+1} of each 8-row tile: stages them privately (gload_lds), scores
// them, accumulates wave-partial g_agg/m/l. NO in-loop barriers; counted
// s_waitcnt vmcnt(4) keeps the next tile's stage in flight across the tile.
// Scores stored to LDS; epilogue merges wave partials, recomputes x_v
// exactly from stored scores + v (L2), and runs the fused wrv GEMV.
__global__ __launch_bounds__(256, 2) void kC(
    const float* __restrict__ G, const float* __restrict__ sk,
    const float* __restrict__ qkp, const float* __restrict__ v,
    const float* __restrict__ wrv, const float* __restrict__ brv,
    float* __restrict__ om)
{
    __shared__ float4 Gdb[2][4][256];   // [buf][wave][2 rows x 128 f4] swizzled
    __shared__ float4 qk4[1024];        // qkp [8h][128] swizzled ^h; final g_agg later
    __shared__ float  sk_l[2048];       // sk [8h][256y]; p_lds later
    __shared__ float  s_st[2048];       // scores [256y][8h]
    __shared__ float  ml[64];           // [w][m(8),l(8)]

    const int t = threadIdx.x;
    const int lane = t & 63;
    const int w = t >> 6;
    const int bid = blockIdx.x;
    const int b = bid >> 8;

    const char* Grow = (const char*)(G + (size_t)bid * NN * DD);

    // ---- prologue: issue qkp(4) + sk(2) + G tile0 (4) per wave ----
    stage_swz((const char*)(qkp + (size_t)bid * HH * DD), qk4, w, lane);
    {
        const char* skb = (const char*)(sk + (size_t)bid * HH * NN);
        gload_lds16(skb + (size_t)(w * 128 + lane) * 16,      (float4*)sk_l + w * 128);
        gload_lds16(skb + (size_t)(w * 128 + 64 + lane) * 16, (float4*)sk_l + w * 128 + 64);
    }
    stageG(Grow, 0, w, lane, &Gdb[0][w][0]);
    // wait qkp+sk landed (keep G0's 4 loads in flight), then raw barrier
    asm volatile("s_waitcnt vmcnt(4)" ::: "memory");
    __builtin_amdgcn_sched_barrier(0);
    __builtin_amdgcn_s_barrier();

    const int s_ = lane & 15;
    const int g  = lane >> 4;          // 16-lane group -> h-pair {2g,2g+1}
    const int h0 = 2 * g;
    const int yr0 = 2 * w, yr1 = 2 * w + 1;   // wave's rows in tile (swizzle keys)

    float4 gA[8], gB[8];               // g_agg[h] at f4-slots lane / lane+64
    float m[8], l[8];
    #pragma unroll
    for (int h = 0; h < 8; ++h) {
        gA[h] = make_float4(0, 0, 0, 0); gB[h] = make_float4(0, 0, 0, 0);
        m[h] = -3e38f; l[h] = 0.f;
    }

    int cb = 0;
    #pragma unroll 1
    for (int tt = 0; tt < 32; ++tt) {
        __builtin_amdgcn_sched_barrier(0);
        if (tt < 31) {
            stageG(Grow, tt + 1, w, lane, &Gdb[cb ^ 1][w][0]);
            asm volatile("s_waitcnt vmcnt(4)" ::: "memory");
        } else {
            asm volatile("s_waitcnt vmcnt(0)" ::: "memory");
        }
        __builtin_amdgcn_sched_barrier(0);

        const float4* gb = &Gdb[cb][w][0];
        const int gy0 = tt * 8 + yr0, gy1 = tt * 8 + yr1;

        // ---- scores: group g computes (2 rows) x (h0,h0+1) ----
        {
            float a00 = 0, a01 = 0, a10 = 0, a11 = 0;
            #pragma unroll
            for (int i = 0; i < 8; ++i) {
                const int e4 = i * 16 + s_;
                const float4 g0 = gb[(e4 ^ yr0)];
                const float4 g1 = gb[128 + (e4 ^ yr1)];
                const float4 p0 = qk4[h0 * 128 + (e4 ^ h0)];
                const float4 p1 = qk4[(h0 + 1) * 128 + (e4 ^ (h0 + 1))];
                a00 += dot4(g0, p0); a01 += dot4(g0, p1);
                a10 += dot4(g1, p0); a11 += dot4(g1, p1);
            }
            #pragma unroll
            for (int mm = 1; mm < 16; mm <<= 1) {
                a00 += __shfl_xor(a00, mm); a01 += __shfl_xor(a01, mm);
                a10 += __shfl_xor(a10, mm); a11 += __shfl_xor(a11, mm);
            }
            if (s_ < 4) {
                const int yy = s_ & 1, hh = s_ >> 1;
                const float val = yy ? (hh ? a11 : a10) : (hh ? a01 : a00);
                const int h = h0 + hh;
                const int gy = yy ? gy1 : gy0;
                s_st[gy * 8 + h] = val * 0.125f + sk_l[h * 256 + gy];
            }
        }

        // ---- same-wave readback (compiler inserts lgkmcnt) ----
        const float4 sva = *(const float4*)&s_st[gy0 * 8];
        const float4 svb = *(const float4*)&s_st[gy0 * 8 + 4];
        const float4 svc = *(const float4*)&s_st[gy1 * 8];
        const float4 svd = *(const float4*)&s_st[gy1 * 8 + 4];
        const float s0[8] = {sva.x, sva.y, sva.z, sva.w, svb.x, svb.y, svb.z, svb.w};
        const float s1[8] = {svc.x, svc.y, svc.z, svc.w, svd.x, svd.y, svd.z, svd.w};

        const float4 gr0a = gb[(lane ^ yr0)];
        const float4 gr0b = gb[((lane + 64) ^ yr0)];
        const float4 gr1a = gb[128 + (lane ^ yr1)];
        const float4 gr1b = gb[128 + ((lane + 64) ^ yr1)];

        #pragma unroll
        for (int h = 0; h < 8; ++h) {
            const float mn = fmaxf(m[h], fmaxf(s0[h], s1[h]));
            const float rs = __expf(m[h] - mn);
            const float p0 = __expf(s0[h] - mn);
            const float p1 = __expf(s1[h] - mn);
            m[h] = mn;
            l[h] = l[h] * rs + p0 + p1;
            gA[h] = f4fma(p1, gr1a, f4fma(p0, gr0a, f4mul(rs, gA[h])));
            gB[h] = f4fma(p1, gr1b, f4fma(p0, gr0b, f4mul(rs, gB[h])));
        }
        cb ^= 1;
    }

    // ---- epilogue ----
    asm volatile("s_waitcnt vmcnt(0)" ::: "memory");
    __syncthreads();
    if (lane == 0) {
        #pragma unroll
        for (int h = 0; h < 8; ++h) { ml[w * 16 + h] = m[h]; ml[w * 16 + 8 + h] = l[h]; }
    }
    __syncthreads();

    float M[8], Lf[8];
    #pragma unroll
    for (int h = 0; h < 8; ++h) {
        const float m0 = ml[h], m1 = ml[16 + h], m2 = ml[32 + h], m3 = ml[48 + h];
        const float mm = fmaxf(fmaxf(m0, m1), fmaxf(m2, m3));
        M[h] = mm;
        Lf[h] = __expf(m0 - mm) * ml[8 + h]  + __expf(m1 - mm) * ml[24 + h]
              + __expf(m2 - mm) * ml[40 + h] + __expf(m3 - mm) * ml[56 + h];
    }
    // scale own partial by exp(m_w - M)
    #pragma unroll
    for (int h = 0; h < 8; ++h) {
        const float ws = __expf(m[h] - M[h]);
        gA[h] = f4mul(ws, gA[h]); gB[h] = f4mul(ws, gB[h]);
    }
    float4* rA = &Gdb[0][0][0];
    float4* rB = &Gdb[1][0][0];
    if (w == 2) {
        #pragma unroll
        for (int h = 0; h < 8; ++h) { rA[h * 128 + lane] = gA[h]; rA[h * 128 + 64 + lane] = gB[h]; }
    }
    if (w == 3) {
        #pragma unroll
        for (int h = 0; h < 8; ++h) { rB[h * 128 + lane] = gA[h]; rB[h * 128 + 64 + lane] = gB[h]; }
    }
    __syncthreads();
    if (w == 0) {
        #pragma unroll
        for (int h = 0; h < 8; ++h) {
            gA[h].x += rA[h*128+lane].x; gA[h].y += rA[h*128+lane].y; gA[h].z += rA[h*128+lane].z; gA[h].w += rA[h*128+lane].w;
            gB[h].x += rA[h*128+64+lane].x; gB[h].y += rA[h*128+64+lane].y; gB[h].z += rA[h*128+64+lane].z; gB[h].w += rA[h*128+64+lane].w;
        }
    }
    if (w == 1) {
        #pragma unroll
        for (int h = 0; h < 8; ++h) {
            gA[h].x += rB[h*128+lane].x; gA[h].y += rB[h*128+lane].y; gA[h].z += rB[h*128+lane].z; gA[h].w += rB[h*128+lane].w;
            gB[h].x += rB[h*128+64+lane].x; gB[h].y += rB[h*128+64+lane].y; gB[h].z += rB[h*128+64+lane].z; gB[h].w += rB[h*128+64+lane].w;
        }
    }
    __syncthreads();
    if (w == 1) {
        #pragma unroll
        for (int h = 0; h < 8; ++h) { rA[h * 128 + lane] = gA[h]; rA[h * 128 + 64 + lane] = gB[h]; }
    }
    __syncthreads();
    if (w == 0) {
        #pragma unroll
        for (int h = 0; h < 8; ++h) {
            gA[h].x += rA[h*128+lane].x; gA[h].y += rA[h*128+lane].y; gA[h].z += rA[h*128+lane].z; gA[h].w += rA[h*128+lane].w;
            gB[h].x += rA[h*128+64+lane].x; gB[h].y += rA[h*128+64+lane].y; gB[h].z += rA[h*128+64+lane].z; gB[h].w += rA[h*128+64+lane].w;
            qk4[h * 128 + lane] = gA[h];           // final g_agg, unswizzled
            qk4[h * 128 + 64 + lane] = gB[h];
        }
    }
    // p_lds = exp(s - M) into sk_l (overwrite); publish Lf
    if (t == 0) {
        #pragma unroll
        for (int h = 0; h < 8; ++h) ml[h] = Lf[h];
    }
    {
        #pragma unroll
        for (int h = 0; h < 8; ++h) sk_l[t * 8 + h] = __expf(s_st[t * 8 + h] - M[h]);
    }
    __syncthreads();

    const float* vb = v + (size_t)(b * NN) * DD;
    #pragma unroll
    for (int jj = 0; jj < 2; ++jj) {
        const int o = jj * 256 + t;
        const int h = o >> 6, d = o & 63;
        const float4* wr4 = (const float4*)(wrv + (size_t)o * DD);
        const float4* gf = (const float4*)qk4 + h * 128;
        float acc = 0;
        #pragma unroll 4
        for (int e4 = 0; e4 < 128; ++e4) acc += dot4(wr4[e4], gf[e4]);
        float xv = 0;
        const float* vc = vb + h * 64 + d;
        #pragma unroll 4
        for (int y = 0; y < 256; ++y) xv += sk_l[y * 8 + h] * vc[(size_t)y * DD];
        om[(size_t)bid * DD + o] = (xv + acc) / ml[h] + brv[o];
    }
}

// ---------------- kE ----------------
__global__ __launch_bounds__(256) void kE(
    const float* __restrict__ xl, const float* __restrict__ xr,
    float* __restrict__ ng)
{
    const int t = threadIdx.x;
    const int blk = blockIdx.x;
    const int bid = blk >> 2;
    const int yc = blk & 3;
    const int b = bid >> 8;
    const int o4 = t & 127;
    const int yh = t >> 7;
    const float4 left = ((const float4*)xl)[(size_t)bid * 128 + o4];
    const float4* xr4 = (const float4*)xr + (size_t)b * NN * 128;
    f4raw* out4 = (f4raw*)ng + (size_t)bid * NN * 128;
    for (int y = yc * 64 + yh; y < yc * 64 + 64; y += 2) {
        const float4 rr = xr4[y * 128 + o4];
        f4raw s;
        s.x = left.x + rr.x; s.y = left.y + rr.y;
        s.z = left.z + rr.z; s.w = left.w + rr.w;
        __builtin_nontemporal_store(s, &out4[y * 128 + o4]);
    }
}

extern "C" void kernel_launch(void* const* d_in, const int* in_sizes, int n_in,
                              void* d_out, int out_size, void* d_ws, size_t ws_size,
                              hipStream_t stream)
{
    (void)in_sizes; (void)n_in; (void)out_size; (void)ws_size;
    const float* x    = (const float*)d_in[0];
    const float* G    = (const float*)d_in[1];
    const unsigned char* mask = (const unsigned char*)d_in[2];
    const float* wq  = (const float*)d_in[3];  const float* bq  = (const float*)d_in[4];
    const float* wk  = (const float*)d_in[5];  const float* bk  = (const float*)d_in[6];
    const float* wv  = (const float*)d_in[7];  const float* bv  = (const float*)d_in[8];
    const float* wo  = (const float*)d_in[9];  const float* bo  = (const float*)d_in[10];
    const float* wl  = (const float*)d_in[11]; const float* bl  = (const float*)d_in[12];
    const float* wr  = (const float*)d_in[13]; const float* br  = (const float*)d_in[14];
    const float* wrk = (const float*)d_in[15]; /* brk unused: softmax-invariant */
    const float* wrv = (const float*)d_in[17]; const float* brv = (const float*)d_in[18];

    float* out  = (float*)d_out;
    float* fout = out;                          // [B,N,D]
    float* ng   = out + (size_t)BB * NN * DD;   // [B,N,N,D]

    // Scratch in the tail of the ng region: all consumed before kE overwrites.
    const size_t ng_f  = (size_t)BB * NN * NN * DD;   // 67,108,864
    const size_t row_f = (size_t)BB * NN * DD;        // 262,144
    const size_t total = row_f * 16;                  // q,k,v,qkp(8),skp(4),om
    float* base = ng + ng_f - total;
    float* q    = base;
    float* k    = q   + row_f;
    float* vv_  = k   + row_f;
    float* qkp  = vv_ + row_f;          // row_f * 8
    float* skp  = qkp + row_f * 8;      // row_f * 4
    float* om   = skp + row_f * 4;      // row_f
    float* xl = (float*)d_ws;           // survives into kE -> d_ws
    float* xr = xl + row_f;

    kProj<<<768, 64, 0, stream>>>(x, wq, bq, wk, bk, wv, bv, q, k, vv_);
    kQkp <<<2048, 256, 0, stream>>>(q, wrk, qkp);
    kSk  <<<2048, 256, 0, stream>>>(q, k, mask, skp);
    kC   <<<512, 256, 0, stream>>>(G, skp, qkp, vv_, wrv, brv, om);
    kProj<<<768, 64, 0, stream>>>(om, wo, bo, wl, bl, wr, br, fout, xl, xr);
    kE   <<<2048, 256, 0, stream>>>(xl, xr, ng);
}